// Round 7
// baseline (1387.698 us; speedup 1.0000x reference)
//
#include <hip/hip_runtime.h>

#define NN 50000
#define HH 202
#define EE 100000
#define PMX 1024
#define NKT 7          // k-steps of 32 (K padded to 224; B packs zero-padded)
#define PKSZ (13 * NKT * 64 * 8)   // ushorts per B pack = 46592
#define NEDG (6 * EE)

typedef __attribute__((ext_vector_type(8))) short short8;
typedef __attribute__((ext_vector_type(4))) float v4f;

union U8 { unsigned int u[4]; short8 s; };

__device__ __forceinline__ float sigf(float x) { return 1.0f / (1.0f + expf(-x)); }

__device__ __forceinline__ unsigned short f2bf(float x) {
    unsigned int u = __float_as_uint(x);
    unsigned int r = (u + 0x7fffu + ((u >> 16) & 1u)) >> 16;
    return (unsigned short)r;
}
__device__ __forceinline__ float bf2f(unsigned short u) {
    return __uint_as_float(((unsigned int)u) << 16);
}

__device__ __forceinline__ unsigned int cvtpk(float lo, float hi) {
    unsigned int r;
    asm("v_cvt_pk_bf16_f32 %0, %1, %2" : "=v"(r) : "v"(lo), "v"(hi));
    return r;
}

// Load an MFMA A-fragment (8 bf16) for this lane directly from a row of f32.
// rowp = clamped row base; k = kt*32 + lh*8 + j. Tail (kt==6) masked so no
// access ever passes rowp+202; k>=202 lanes return 0 (B pack is 0 there anyway).
__device__ __forceinline__ short8 load_a(const float* rowp, int kt, int lh) {
    U8 u;
    if (kt < 6) {
        const float2* p = (const float2*)(rowp + kt * 32 + lh * 8);
        float2 v0 = p[0], v1 = p[1], v2 = p[2], v3 = p[3];
        u.u[0] = cvtpk(v0.x, v0.y); u.u[1] = cvtpk(v1.x, v1.y);
        u.u[2] = cvtpk(v2.x, v2.y); u.u[3] = cvtpk(v3.x, v3.y);
    } else if (lh == 0) {
        const float2* p = (const float2*)(rowp + 192);
        float2 v0 = p[0], v1 = p[1], v2 = p[2], v3 = p[3];
        u.u[0] = cvtpk(v0.x, v0.y); u.u[1] = cvtpk(v1.x, v1.y);
        u.u[2] = cvtpk(v2.x, v2.y); u.u[3] = cvtpk(v3.x, v3.y);
    } else if (lh == 1) {
        float2 v = *(const float2*)(rowp + 200);
        u.u[0] = cvtpk(v.x, v.y); u.u[1] = 0; u.u[2] = 0; u.u[3] = 0;
    } else {
        u.u[0] = 0; u.u[1] = 0; u.u[2] = 0; u.u[3] = 0;
    }
    return u.s;
}

// gate[p][j] = bf16( 2*sigmoid(sum_k pt[p][k]*pos_W[k][j] + pos_b[j]) )
__global__ void gate_kernel(const float* __restrict__ pos_W, const float* __restrict__ pos_b,
                            unsigned short* __restrict__ gate) {
    int p = blockIdx.x;
    __shared__ float pt[HH];
    int t = threadIdx.x;
    if (t < HH) {
        float v;
        if (t < 101) {
            float invf = expf(-(2.0f * t / 202.0f) * 9.210340371976184f); // ln(10000)
            v = sinf((float)p * invf);
        } else {
            int k = t - 101;
            float invf = expf(-(2.0f * k / 202.0f) * 9.210340371976184f);
            v = cosf((float)p * invf);
        }
        pt[t] = v;
    }
    __syncthreads();
    for (int j = t; j < HH; j += blockDim.x) {
        float acc = pos_b[j];
        for (int k = 0; k < HH; ++k) acc += pt[k] * pos_W[k * HH + j];
        gate[p * HH + j] = f2bf(2.0f * sigf(acc));
    }
}

// Pack B into MFMA fragment order, f32 -> bf16 (zeros for k or j >= 202).
// BP[((cf*NKT + kt)*64 + l)*8 + jj] = B[k][j], k = kt*32 + (l>>4)*8 + jj, j = cf*16 + (l&15)
__global__ void pack_kernel(const float* __restrict__ S, int ldb, int row0, int col0, int mode,
                            unsigned short* __restrict__ BP) {
    int idx = blockIdx.x * blockDim.x + threadIdx.x;
    if (idx >= PKSZ) return;
    int jj = idx & 7;
    int l = (idx >> 3) & 63;
    int r2 = idx >> 9;             // cf*NKT + kt
    int cf = r2 / NKT, kt = r2 - cf * NKT;
    int k = kt * 32 + ((l >> 4) << 3) + jj;
    int j = cf * 16 + (l & 15);
    float v = 0.0f;
    if (k < HH && j < HH)
        v = mode ? S[(size_t)(row0 + j) * HH + k] : S[(size_t)k * ldb + col0 + j];
    BP[idx] = f2bf(v);
}

__global__ void count_kernel(const int* __restrict__ el, int* __restrict__ cnt) {
    int idx = blockIdx.x * blockDim.x + threadIdx.x;
    if (idx >= NEDG) return;
    int ty = idx / EE, e = idx - ty * EE;
    int2 pr = (ty < 3) ? reinterpret_cast<const int2*>(el)[ty * EE + e]
                       : reinterpret_cast<const int2*>(el)[(ty - 3) * EE + e];
    int tg = (ty < 3) ? pr.y : pr.x;
    atomicAdd(&cnt[tg], 1);
}

__global__ void scan1_kernel(const int* __restrict__ cnt, int* __restrict__ off,
                             int* __restrict__ bsum) {
    __shared__ int sd[256];
    int t = threadIdx.x, i = blockIdx.x * 256 + t;
    int v = (i < NN) ? cnt[i] : 0;
    sd[t] = v;
    __syncthreads();
    for (int s = 1; s < 256; s <<= 1) {
        int u = (t >= s) ? sd[t - s] : 0;
        __syncthreads();
        sd[t] += u;
        __syncthreads();
    }
    if (i < NN) off[i] = sd[t] - v;
    if (t == 255) bsum[blockIdx.x] = sd[255];
}

__global__ void scan2_kernel(int* __restrict__ bsum, int nb) {
    __shared__ int sd[256];
    int t = threadIdx.x;
    int v = (t < nb) ? bsum[t] : 0;
    sd[t] = v;
    __syncthreads();
    for (int s = 1; s < 256; s <<= 1) {
        int u = (t >= s) ? sd[t - s] : 0;
        __syncthreads();
        sd[t] += u;
        __syncthreads();
    }
    if (t < nb) bsum[t] = sd[t] - v;   // exclusive
}

__global__ void scan3_kernel(int* __restrict__ off, const int* __restrict__ bsum,
                             int* __restrict__ cursor) {
    int i = blockIdx.x * 256 + threadIdx.x;
    if (i < NN) {
        int o = off[i] + bsum[blockIdx.x];
        off[i] = o;
        cursor[i] = o;
    }
    if (i == 0) off[NN] = NEDG;
}

__global__ void inv_kernel(const int* __restrict__ cnt, float* __restrict__ inv) {
    int n = blockIdx.x * blockDim.x + threadIdx.x;
    if (n < NN) inv[n] = 1.0f / (float)max(cnt[n], 1);
}

// EDG[slot] = src(17b) << 13 | ty(3b) << 10 | pos(10b), grouped by target via cursor
__global__ void fill_kernel(const int* __restrict__ el, const int* __restrict__ pl,
                            int* __restrict__ cursor, int* __restrict__ edg) {
    int idx = blockIdx.x * blockDim.x + threadIdx.x;
    if (idx >= NEDG) return;
    int ty = idx / EE, e = idx - ty * EE;
    int s, tg;
    if (ty < 3) {
        int2 pr = reinterpret_cast<const int2*>(el)[ty * EE + e];
        s = pr.x; tg = pr.y;
    } else {
        int2 pr = reinterpret_cast<const int2*>(el)[(ty - 3) * EE + e];
        s = pr.y; tg = pr.x;
    }
    int p = pl[(ty % 3) * EE + e];
    p = min(max(p, 0), PMX - 1);
    int slot = atomicAdd(&cursor[tg], 1);
    edg[slot] = (s << 13) | (ty << 10) | p;
}

// chunks[ty][n][j] (bf16) for all 6 ty. M=64 tile; 4 waves column-split {4,3,3,3} cfs,
// each wave all 64 rows (4 row-frags). No LDS, no barriers: A fragments loaded
// straight from global (L1/L2-cached across the 6 ty), B packs streamed from L2.
__global__ __launch_bounds__(256, 3) void prop_fused(
    const float* __restrict__ A, const unsigned short* __restrict__ BPp,
    const float* __restrict__ msg_b,
    unsigned short* __restrict__ CH0, unsigned short* __restrict__ CH45) {
    const int t = threadIdx.x;
    const int w = t >> 6;
    const int l = t & 63;
    const int lm = l & 15, lh = l >> 4;
    const int cs = w * 3 + (w > 0);     // 0,4,7,10
    const int ncf = w ? 3 : 4;
    const int base = blockIdx.x * 64;

    const float* rowp[4];
#pragma unroll
    for (int rf = 0; rf < 4; ++rf) {
        int row = base + rf * 16 + lm;
        rowp[rf] = A + (size_t)min(row, NN - 1) * HH;
    }

#pragma unroll 1
    for (int ty = 0; ty < 6; ++ty) {
        const unsigned short* BP = BPp + (size_t)ty * PKSZ;
        v4f acc[4][4];   // [ci][rf]
#pragma unroll
        for (int ci = 0; ci < 4; ++ci)
#pragma unroll
            for (int rf = 0; rf < 4; ++rf) acc[ci][rf] = (v4f){0.f, 0.f, 0.f, 0.f};

#pragma unroll 2
        for (int kt = 0; kt < NKT; ++kt) {
            short8 a[4];
#pragma unroll
            for (int rf = 0; rf < 4; ++rf) a[rf] = load_a(rowp[rf], kt, lh);
#pragma unroll
            for (int ci = 0; ci < 4; ++ci) {
                if (ci < ncf) {
                    short8 b = *reinterpret_cast<const short8*>(
                        &BP[((size_t)((cs + ci) * NKT + kt) * 64 + l) * 8]);
#pragma unroll
                    for (int rf = 0; rf < 4; ++rf)
                        acc[ci][rf] = __builtin_amdgcn_mfma_f32_16x16x32_bf16(
                            a[rf], b, acc[ci][rf], 0, 0, 0);
                }
            }
        }

        unsigned short* CH = (ty < 4) ? CH0 + (size_t)ty * NN * HH
                                      : CH45 + (size_t)(ty - 4) * NN * HH;
#pragma unroll
        for (int ci = 0; ci < 4; ++ci) {
            if (ci < ncf) {
                int col = (cs + ci) * 16 + lm;
                if (col < HH) {
                    float bb = msg_b[ty * HH + col];
#pragma unroll
                    for (int rf = 0; rf < 4; ++rf) {
#pragma unroll
                        for (int r = 0; r < 4; ++r) {
                            int row = base + rf * 16 + lh * 4 + r;
                            if (row < NN) CH[(size_t)row * HH + col] = f2bf(acc[ci][rf][r] + bb);
                        }
                    }
                }
            }
        }
    }
}

// one wave per target node: MSG[n] = inv[n] * sum_edges chunk[ty][src] * gate[pos]
__global__ void agg_kernel(const unsigned short* __restrict__ CH0,
                           const unsigned short* __restrict__ CH45,
                           const int* __restrict__ off, const int* __restrict__ edg,
                           const unsigned short* __restrict__ gate,
                           const float* __restrict__ inv, float* __restrict__ msg) {
    int n = blockIdx.x * 4 + (threadIdx.x >> 6);
    if (n >= NN) return;
    int lane = threadIdx.x & 63;
    int s0 = off[n], s1 = off[n + 1];
    int j0 = lane, j1 = lane + 64, j2 = lane + 128, j3 = lane + 192;
    float a0 = 0.f, a1 = 0.f, a2 = 0.f, a3 = 0.f;
    for (int i = s0; i < s1; ++i) {
        int rec = edg[i];
        int src = rec >> 13;
        int ty = (rec >> 10) & 7;
        int p = rec & 1023;
        const unsigned short* cr =
            ((ty < 4) ? CH0 + (size_t)ty * NN * HH : CH45 + (size_t)(ty - 4) * NN * HH)
            + (size_t)src * HH;
        const unsigned short* gr = gate + (size_t)p * HH;
        a0 += bf2f(cr[j0]) * bf2f(gr[j0]);
        a1 += bf2f(cr[j1]) * bf2f(gr[j1]);
        a2 += bf2f(cr[j2]) * bf2f(gr[j2]);
        if (j3 < HH) a3 += bf2f(cr[j3]) * bf2f(gr[j3]);
    }
    float iv = inv[n];
    float* mr = msg + (size_t)n * HH;
    mr[j0] = a0 * iv; mr[j1] = a1 * iv; mr[j2] = a2 * iv;
    if (j3 < HH) mr[j3] = a3 * iv;
}

// Fused GRU, no LDS. M=64 tile; 4 waves column-split {4,3,3,3}, each wave all
// 64 rows (4 row-frags). 4 sequential K-loops (A rows L1-cached). In step 1
// h == hsrc (in-place update): NO __restrict__ on these two, and a single
// __syncthreads() separates the last hsrc read (K-loop 4) from the epilogue
// stores, so no wave overwrites rows another wave is still streaming.
// Blocks touch only their own 64 rows -> no inter-block hazard.
__global__ __launch_bounds__(256, 2) void gru_fused(
    float* h, const float* hsrc, const float* __restrict__ msg,
    const unsigned short* __restrict__ BPir, const unsigned short* __restrict__ BPiz,
    const unsigned short* __restrict__ BPin, const unsigned short* __restrict__ BPhr,
    const unsigned short* __restrict__ BPhz, const unsigned short* __restrict__ BPhn,
    const float* __restrict__ bih, const float* __restrict__ bhh) {
    const int t = threadIdx.x;
    const int w = t >> 6;
    const int l = t & 63;
    const int lm = l & 15, lh = l >> 4;
    const int cs = w * 3 + (w > 0);     // 0,4,7,10
    const int ncf = w ? 3 : 4;
    const int base = blockIdx.x * 64;

    const float* rowph[4];
    const float* rowpm[4];
#pragma unroll
    for (int rf = 0; rf < 4; ++rf) {
        int row = base + rf * 16 + lm;
        size_t ro = (size_t)min(row, NN - 1) * HH;
        rowph[rf] = hsrc + ro;
        rowpm[rf] = msg + ro;
    }

    v4f P1[4][4], P2[4][4];
#pragma unroll
    for (int ci = 0; ci < 4; ++ci)
#pragma unroll
        for (int rf = 0; rf < 4; ++rf) P1[ci][rf] = (v4f){0.f, 0.f, 0.f, 0.f};

    // loop 1: P1 = msg@Wir + h@Whr
#pragma unroll 1
    for (int kt = 0; kt < NKT; ++kt) {
        short8 ah[4], am[4];
#pragma unroll
        for (int rf = 0; rf < 4; ++rf) {
            ah[rf] = load_a(rowph[rf], kt, lh);
            am[rf] = load_a(rowpm[rf], kt, lh);
        }
#pragma unroll
        for (int ci = 0; ci < 4; ++ci) {
            if (ci < ncf) {
                size_t bo = ((size_t)((cs + ci) * NKT + kt) * 64 + l) * 8;
                short8 bir = *reinterpret_cast<const short8*>(&BPir[bo]);
                short8 bhr = *reinterpret_cast<const short8*>(&BPhr[bo]);
#pragma unroll
                for (int rf = 0; rf < 4; ++rf) {
                    P1[ci][rf] = __builtin_amdgcn_mfma_f32_16x16x32_bf16(am[rf], bir, P1[ci][rf], 0, 0, 0);
                    P1[ci][rf] = __builtin_amdgcn_mfma_f32_16x16x32_bf16(ah[rf], bhr, P1[ci][rf], 0, 0, 0);
                }
            }
        }
    }
    // r = sig(P1 + br)
#pragma unroll
    for (int ci = 0; ci < 4; ++ci) {
        if (ci < ncf) {
            int col = (cs + ci) * 16 + lm;
            float br = (col < HH) ? (bih[col] + bhh[col]) : 0.f;
#pragma unroll
            for (int rf = 0; rf < 4; ++rf)
#pragma unroll
                for (int r = 0; r < 4; ++r)
                    P1[ci][rf][r] = sigf(P1[ci][rf][r] + br);
        }
    }

    // loop 2: P2 = h@Whn
#pragma unroll
    for (int ci = 0; ci < 4; ++ci)
#pragma unroll
        for (int rf = 0; rf < 4; ++rf) P2[ci][rf] = (v4f){0.f, 0.f, 0.f, 0.f};
#pragma unroll 2
    for (int kt = 0; kt < NKT; ++kt) {
        short8 ah[4];
#pragma unroll
        for (int rf = 0; rf < 4; ++rf) ah[rf] = load_a(rowph[rf], kt, lh);
#pragma unroll
        for (int ci = 0; ci < 4; ++ci) {
            if (ci < ncf) {
                size_t bo = ((size_t)((cs + ci) * NKT + kt) * 64 + l) * 8;
                short8 bhn = *reinterpret_cast<const short8*>(&BPhn[bo]);
#pragma unroll
                for (int rf = 0; rf < 4; ++rf)
                    P2[ci][rf] = __builtin_amdgcn_mfma_f32_16x16x32_bf16(ah[rf], bhn, P2[ci][rf], 0, 0, 0);
            }
        }
    }
    // P2 = bin + r*(P2 + bnh)
#pragma unroll
    for (int ci = 0; ci < 4; ++ci) {
        if (ci < ncf) {
            int col = (cs + ci) * 16 + lm;
            float bn_i = (col < HH) ? bih[404 + col] : 0.f;
            float bn_h = (col < HH) ? bhh[404 + col] : 0.f;
#pragma unroll
            for (int rf = 0; rf < 4; ++rf)
#pragma unroll
                for (int r = 0; r < 4; ++r)
                    P2[ci][rf][r] = bn_i + P1[ci][rf][r] * (P2[ci][rf][r] + bn_h);
        }
    }

    // loop 3: P2 += msg@Win; then n = tanh(P2)
#pragma unroll 2
    for (int kt = 0; kt < NKT; ++kt) {
        short8 am[4];
#pragma unroll
        for (int rf = 0; rf < 4; ++rf) am[rf] = load_a(rowpm[rf], kt, lh);
#pragma unroll
        for (int ci = 0; ci < 4; ++ci) {
            if (ci < ncf) {
                size_t bo = ((size_t)((cs + ci) * NKT + kt) * 64 + l) * 8;
                short8 bin_ = *reinterpret_cast<const short8*>(&BPin[bo]);
#pragma unroll
                for (int rf = 0; rf < 4; ++rf)
                    P2[ci][rf] = __builtin_amdgcn_mfma_f32_16x16x32_bf16(am[rf], bin_, P2[ci][rf], 0, 0, 0);
            }
        }
    }
#pragma unroll
    for (int ci = 0; ci < 4; ++ci)
        if (ci < ncf)
#pragma unroll
            for (int rf = 0; rf < 4; ++rf)
#pragma unroll
                for (int r = 0; r < 4; ++r)
                    P2[ci][rf][r] = tanhf(P2[ci][rf][r]);

    // loop 4: P1 = msg@Wiz + h@Whz
#pragma unroll
    for (int ci = 0; ci < 4; ++ci)
#pragma unroll
        for (int rf = 0; rf < 4; ++rf) P1[ci][rf] = (v4f){0.f, 0.f, 0.f, 0.f};
#pragma unroll 1
    for (int kt = 0; kt < NKT; ++kt) {
        short8 ah[4], am[4];
#pragma unroll
        for (int rf = 0; rf < 4; ++rf) {
            ah[rf] = load_a(rowph[rf], kt, lh);
            am[rf] = load_a(rowpm[rf], kt, lh);
        }
#pragma unroll
        for (int ci = 0; ci < 4; ++ci) {
            if (ci < ncf) {
                size_t bo = ((size_t)((cs + ci) * NKT + kt) * 64 + l) * 8;
                short8 biz = *reinterpret_cast<const short8*>(&BPiz[bo]);
                short8 bhz = *reinterpret_cast<const short8*>(&BPhz[bo]);
#pragma unroll
                for (int rf = 0; rf < 4; ++rf) {
                    P1[ci][rf] = __builtin_amdgcn_mfma_f32_16x16x32_bf16(am[rf], biz, P1[ci][rf], 0, 0, 0);
                    P1[ci][rf] = __builtin_amdgcn_mfma_f32_16x16x32_bf16(ah[rf], bhz, P1[ci][rf], 0, 0, 0);
                }
            }
        }
    }

    // All hsrc streaming reads are complete for every wave past this barrier
    // (HIP __syncthreads drains vmcnt before s_barrier). Only then may any
    // wave overwrite h rows. The hv re-read below touches only this wave's
    // own columns, which only this wave writes.
    __syncthreads();

    // z = sig(P1+bz); h' = (1-z)*n + z*h
#pragma unroll
    for (int ci = 0; ci < 4; ++ci) {
        if (ci < ncf) {
            int col = (cs + ci) * 16 + lm;
            if (col < HH) {
                float bz = bih[202 + col] + bhh[202 + col];
#pragma unroll
                for (int rf = 0; rf < 4; ++rf) {
#pragma unroll
                    for (int r = 0; r < 4; ++r) {
                        int row = base + rf * 16 + lh * 4 + r;
                        if (row < NN) {
                            float z = sigf(P1[ci][rf][r] + bz);
                            float hv = hsrc[(size_t)row * HH + col];
                            h[(size_t)row * HH + col] = (1.0f - z) * P2[ci][rf][r] + z * hv;
                        }
                    }
                }
            }
        }
    }
}

extern "C" void kernel_launch(void* const* d_in, const int* in_sizes, int n_in,
                              void* d_out, int out_size, void* d_ws, size_t ws_size,
                              hipStream_t stream) {
    const float* node_states = (const float*)d_in[0];
    const int*   el          = (const int*)d_in[1];
    const int*   pl          = (const int*)d_in[2];
    const float* msg_W       = (const float*)d_in[3];
    const float* msg_b       = (const float*)d_in[4];
    const float* pos_W       = (const float*)d_in[5];
    const float* pos_b       = (const float*)d_in[6];
    const float* gWih        = (const float*)d_in[7];
    const float* gWhh        = (const float*)d_in[8];
    const float* gbih        = (const float*)d_in[9];
    const float* gbhh        = (const float*)d_in[10];

    float* out  = (float*)d_out;
    float* h    = out;                               // [N,H] final h
    float* out2 = out + (size_t)NN * HH;             // chunks ty=4,5 during steps; node_states at end

    unsigned short* CH0  = (unsigned short*)d_ws;                    // 4 slabs bf16 [N,H]
    unsigned short* CH45 = (unsigned short*)out2;                    // 2 slabs bf16 [N,H]
    float* MSG  = (float*)(CH0 + (size_t)4 * NN * HH);               // [N,H] f32
    unsigned short* GATE = (unsigned short*)(MSG + (size_t)NN * HH); // [1024,H] bf16
    float* INV  = (float*)(GATE + (size_t)PMX * HH);                 // [N]
    int* CNT    = (int*)(INV + NN);                                  // [N]
    int* OFF    = CNT + NN;                                          // [N+4]
    int* CUR    = OFF + NN + 4;                                      // [N]
    int* BS     = CUR + NN;                                          // [256]
    int* EDG    = BS + 256;                                          // [600000]
    unsigned short* BPA = (unsigned short*)(EDG + NEDG);             // 12 packs
    unsigned short* BPp  = BPA;
    unsigned short* BPir = BPA + (size_t)6 * PKSZ;
    unsigned short* BPiz = BPA + (size_t)7 * PKSZ;
    unsigned short* BPin = BPA + (size_t)8 * PKSZ;
    unsigned short* BPhr = BPA + (size_t)9 * PKSZ;
    unsigned short* BPhz = BPA + (size_t)10 * PKSZ;
    unsigned short* BPhn = BPA + (size_t)11 * PKSZ;

    const size_t NH = (size_t)NN * HH;
    hipMemsetAsync(CNT, 0, NN * sizeof(int), stream);
    gate_kernel<<<PMX, 256, 0, stream>>>(pos_W, pos_b, GATE);
    const int pkb = (PKSZ + 255) / 256;
    for (int ty = 0; ty < 6; ++ty)
        pack_kernel<<<pkb, 256, 0, stream>>>(msg_W, 1212, 0, ty * HH, 0, BPp + (size_t)ty * PKSZ);
    pack_kernel<<<pkb, 256, 0, stream>>>(gWih, 0, 0,   0, 1, BPir);
    pack_kernel<<<pkb, 256, 0, stream>>>(gWih, 0, 202, 0, 1, BPiz);
    pack_kernel<<<pkb, 256, 0, stream>>>(gWih, 0, 404, 0, 1, BPin);
    pack_kernel<<<pkb, 256, 0, stream>>>(gWhh, 0, 0,   0, 1, BPhr);
    pack_kernel<<<pkb, 256, 0, stream>>>(gWhh, 0, 202, 0, 1, BPhz);
    pack_kernel<<<pkb, 256, 0, stream>>>(gWhh, 0, 404, 0, 1, BPhn);

    const int nsb = (NN + 255) / 256;    // 196
    count_kernel<<<(NEDG + 255) / 256, 256, 0, stream>>>(el, CNT);
    scan1_kernel<<<nsb, 256, 0, stream>>>(CNT, OFF, BS);
    scan2_kernel<<<1, 256, 0, stream>>>(BS, nsb);
    scan3_kernel<<<nsb, 256, 0, stream>>>(OFF, BS, CUR);
    inv_kernel<<<nsb, 256, 0, stream>>>(CNT, INV);
    fill_kernel<<<(NEDG + 255) / 256, 256, 0, stream>>>(el, pl, CUR, EDG);

    const int gblocks = (NN + 63) / 64;  // 782
    for (int step = 0; step < 2; ++step) {
        const float* hsrc = (step == 0) ? node_states : h;
        prop_fused<<<gblocks, 256, 0, stream>>>(hsrc, BPp, msg_b, CH0, CH45);
        agg_kernel<<<(NN + 3) / 4, 256, 0, stream>>>(CH0, CH45, OFF, EDG, GATE, INV, MSG);
        gru_fused<<<gblocks, 256, 0, stream>>>(h, hsrc, MSG, BPir, BPiz, BPin,
                                               BPhr, BPhz, BPhn, gbih, gbhh);
    }
    hipMemcpyAsync(out2, node_states, NH * sizeof(float), hipMemcpyDeviceToDevice, stream);
}

// Round 8
// 858.272 us; speedup vs baseline: 1.6169x; 1.6169x over previous
//
#include <hip/hip_runtime.h>

#define NN 50000
#define HH 202
#define EE 100000
#define PMX 1024
#define NKT 7          // k-steps of 32 (K padded to 224; B packs zero-padded)
#define LDA 232        // LDS A row stride in ushorts
#define PKSZ (13 * NKT * 64 * 8)   // ushorts per B pack = 46592
#define NEDG (6 * EE)

typedef __attribute__((ext_vector_type(8))) short short8;
typedef __attribute__((ext_vector_type(4))) float v4f;

__device__ __forceinline__ float sigf(float x) { return 1.0f / (1.0f + expf(-x)); }

__device__ __forceinline__ unsigned short f2bf(float x) {
    unsigned int u = __float_as_uint(x);
    unsigned int r = (u + 0x7fffu + ((u >> 16) & 1u)) >> 16;
    return (unsigned short)r;
}
__device__ __forceinline__ float bf2f(unsigned short u) {
    return __uint_as_float(((unsigned int)u) << 16);
}

// gate[p][j] = bf16( 2*sigmoid(sum_k pt[p][k]*pos_W[k][j] + pos_b[j]) )
__global__ void gate_kernel(const float* __restrict__ pos_W, const float* __restrict__ pos_b,
                            unsigned short* __restrict__ gate) {
    int p = blockIdx.x;
    __shared__ float pt[HH];
    int t = threadIdx.x;
    if (t < HH) {
        float v;
        if (t < 101) {
            float invf = expf(-(2.0f * t / 202.0f) * 9.210340371976184f); // ln(10000)
            v = sinf((float)p * invf);
        } else {
            int k = t - 101;
            float invf = expf(-(2.0f * k / 202.0f) * 9.210340371976184f);
            v = cosf((float)p * invf);
        }
        pt[t] = v;
    }
    __syncthreads();
    for (int j = t; j < HH; j += blockDim.x) {
        float acc = pos_b[j];
        for (int k = 0; k < HH; ++k) acc += pt[k] * pos_W[k * HH + j];
        gate[p * HH + j] = f2bf(2.0f * sigf(acc));
    }
}

// Pack B into MFMA fragment order, f32 -> bf16 (zeros for k or j >= 202).
// BP[((cf*NKT + kt)*64 + l)*8 + jj] = B[k][j], k = kt*32 + (l>>4)*8 + jj, j = cf*16 + (l&15)
__global__ void pack_kernel(const float* __restrict__ S, int ldb, int row0, int col0, int mode,
                            unsigned short* __restrict__ BP) {
    int idx = blockIdx.x * blockDim.x + threadIdx.x;
    if (idx >= PKSZ) return;
    int jj = idx & 7;
    int l = (idx >> 3) & 63;
    int r2 = idx >> 9;             // cf*NKT + kt
    int cf = r2 / NKT, kt = r2 - cf * NKT;
    int k = kt * 32 + ((l >> 4) << 3) + jj;
    int j = cf * 16 + (l & 15);
    float v = 0.0f;
    if (k < HH && j < HH)
        v = mode ? S[(size_t)(row0 + j) * HH + k] : S[(size_t)k * ldb + col0 + j];
    BP[idx] = f2bf(v);
}

__global__ void count_kernel(const int* __restrict__ el, int* __restrict__ cnt) {
    int idx = blockIdx.x * blockDim.x + threadIdx.x;
    if (idx >= NEDG) return;
    int ty = idx / EE, e = idx - ty * EE;
    int2 pr = (ty < 3) ? reinterpret_cast<const int2*>(el)[ty * EE + e]
                       : reinterpret_cast<const int2*>(el)[(ty - 3) * EE + e];
    int tg = (ty < 3) ? pr.y : pr.x;
    atomicAdd(&cnt[tg], 1);
}

__global__ void scan1_kernel(const int* __restrict__ cnt, int* __restrict__ off,
                             int* __restrict__ bsum) {
    __shared__ int sd[256];
    int t = threadIdx.x, i = blockIdx.x * 256 + t;
    int v = (i < NN) ? cnt[i] : 0;
    sd[t] = v;
    __syncthreads();
    for (int s = 1; s < 256; s <<= 1) {
        int u = (t >= s) ? sd[t - s] : 0;
        __syncthreads();
        sd[t] += u;
        __syncthreads();
    }
    if (i < NN) off[i] = sd[t] - v;
    if (t == 255) bsum[blockIdx.x] = sd[255];
}

__global__ void scan2_kernel(int* __restrict__ bsum, int nb) {
    __shared__ int sd[256];
    int t = threadIdx.x;
    int v = (t < nb) ? bsum[t] : 0;
    sd[t] = v;
    __syncthreads();
    for (int s = 1; s < 256; s <<= 1) {
        int u = (t >= s) ? sd[t - s] : 0;
        __syncthreads();
        sd[t] += u;
        __syncthreads();
    }
    if (t < nb) bsum[t] = sd[t] - v;   // exclusive
}

__global__ void scan3_kernel(int* __restrict__ off, const int* __restrict__ bsum,
                             int* __restrict__ cursor) {
    int i = blockIdx.x * 256 + threadIdx.x;
    if (i < NN) {
        int o = off[i] + bsum[blockIdx.x];
        off[i] = o;
        cursor[i] = o;
    }
    if (i == 0) off[NN] = NEDG;
}

__global__ void inv_kernel(const int* __restrict__ cnt, float* __restrict__ inv) {
    int n = blockIdx.x * blockDim.x + threadIdx.x;
    if (n < NN) inv[n] = 1.0f / (float)max(cnt[n], 1);
}

// EDG[slot] = src(17b) << 13 | ty(3b) << 10 | pos(10b), grouped by target via cursor
__global__ void fill_kernel(const int* __restrict__ el, const int* __restrict__ pl,
                            int* __restrict__ cursor, int* __restrict__ edg) {
    int idx = blockIdx.x * blockDim.x + threadIdx.x;
    if (idx >= NEDG) return;
    int ty = idx / EE, e = idx - ty * EE;
    int s, tg;
    if (ty < 3) {
        int2 pr = reinterpret_cast<const int2*>(el)[ty * EE + e];
        s = pr.x; tg = pr.y;
    } else {
        int2 pr = reinterpret_cast<const int2*>(el)[(ty - 3) * EE + e];
        s = pr.y; tg = pr.x;
    }
    int p = pl[(ty % 3) * EE + e];
    p = min(max(p, 0), PMX - 1);
    int slot = atomicAdd(&cursor[tg], 1);
    edg[slot] = (s << 13) | (ty << 10) | p;
}

// chunks[ty][n][j] (bf16) for all 6 ty. M=64 tile; 4 waves column-split {4,3,3,3} cfs,
// each wave all 64 rows (4 row-frags). A staged in LDS once (reused 6x). Output tile
// staged in LDS (unpadded row-major) then copied out as contiguous uint4 -> full-line
// coalesced stores (fixes the 2.2x write inflation of scattered 2B MFMA-epilogue stores).
__global__ __launch_bounds__(256, 2) void prop_fused(
    const float* __restrict__ A, const unsigned short* __restrict__ BPp,
    const float* __restrict__ msg_b,
    unsigned short* __restrict__ CH0, unsigned short* __restrict__ CH45) {
    __shared__ unsigned short a_lds[64 * LDA];
    __shared__ alignas(16) unsigned short c_lds[64 * HH];
    const int t = threadIdx.x;
    const int w = t >> 6;
    const int l = t & 63;
    const int lm = l & 15, lh = l >> 4;
    const int cs = w * 3 + (w > 0);     // 0,4,7,10
    const int ncf = w ? 3 : 4;
    const int base = blockIdx.x * 64;
    const int vrows = min(64, NN - base);          // 64 or 16 (both %4==0)
    const int nu4 = (vrows * 101) >> 2;            // uint4 count of vrows*404B

    for (int idx = t; idx < 64 * 101; idx += 256) {
        int row = idx / 101;
        int c = idx - row * 101;
        int gn = base + row;
        float2 v = make_float2(0.f, 0.f);
        if (gn < NN) v = *reinterpret_cast<const float2*>(&A[(size_t)gn * HH + c * 2]);
        ushort2 bv; bv.x = f2bf(v.x); bv.y = f2bf(v.y);
        *reinterpret_cast<ushort2*>(&a_lds[row * LDA + c * 2]) = bv;
    }
    for (int idx = t; idx < 64 * 11; idx += 256) {
        int row = idx / 11;
        int c = idx - row * 11;
        ushort2 z; z.x = 0; z.y = 0;
        *reinterpret_cast<ushort2*>(&a_lds[row * LDA + HH + c * 2]) = z;
    }
    __syncthreads();

#pragma unroll 1
    for (int ty = 0; ty < 6; ++ty) {
        const unsigned short* BP = BPp + (size_t)ty * PKSZ;
        v4f acc[4][4];   // [ci][rf]
#pragma unroll
        for (int ci = 0; ci < 4; ++ci)
#pragma unroll
            for (int rf = 0; rf < 4; ++rf) acc[ci][rf] = (v4f){0.f, 0.f, 0.f, 0.f};

#pragma unroll 1
        for (int kt = 0; kt < NKT; ++kt) {
            short8 a[4];
#pragma unroll
            for (int rf = 0; rf < 4; ++rf)
                a[rf] = *reinterpret_cast<const short8*>(
                    &a_lds[(rf * 16 + lm) * LDA + kt * 32 + lh * 8]);
#pragma unroll
            for (int ci = 0; ci < 4; ++ci) {
                if (ci < ncf) {
                    short8 b = *reinterpret_cast<const short8*>(
                        &BP[((size_t)((cs + ci) * NKT + kt) * 64 + l) * 8]);
#pragma unroll
                    for (int rf = 0; rf < 4; ++rf)
                        acc[ci][rf] = __builtin_amdgcn_mfma_f32_16x16x32_bf16(
                            a[rf], b, acc[ci][rf], 0, 0, 0);
                }
            }
        }

        // previous ty's copy-out must be done before we overwrite c_lds
        __syncthreads();
#pragma unroll
        for (int ci = 0; ci < 4; ++ci) {
            if (ci < ncf) {
                int col = (cs + ci) * 16 + lm;
                if (col < HH) {
                    float bb = msg_b[ty * HH + col];
#pragma unroll
                    for (int rf = 0; rf < 4; ++rf) {
#pragma unroll
                        for (int r = 0; r < 4; ++r)
                            c_lds[(rf * 16 + lh * 4 + r) * HH + col] = f2bf(acc[ci][rf][r] + bb);
                    }
                }
            }
        }
        __syncthreads();

        unsigned short* CH = (ty < 4) ? CH0 + (size_t)ty * NN * HH
                                      : CH45 + (size_t)(ty - 4) * NN * HH;
        uint4* dst = reinterpret_cast<uint4*>(CH + (size_t)base * HH);
        const uint4* srcp = reinterpret_cast<const uint4*>(c_lds);
        for (int i = t; i < nu4; i += 256) dst[i] = srcp[i];
    }
}

// one wave per target node: MSG[n] (bf16) = inv[n] * sum_edges chunk[ty][src] * gate[pos]
__global__ void agg_kernel(const unsigned short* __restrict__ CH0,
                           const unsigned short* __restrict__ CH45,
                           const int* __restrict__ off, const int* __restrict__ edg,
                           const unsigned short* __restrict__ gate,
                           const float* __restrict__ inv, unsigned short* __restrict__ msgb) {
    int n = blockIdx.x * 4 + (threadIdx.x >> 6);
    if (n >= NN) return;
    int lane = threadIdx.x & 63;
    int s0 = off[n], s1 = off[n + 1];
    int j0 = lane, j1 = lane + 64, j2 = lane + 128, j3 = lane + 192;
    float a0 = 0.f, a1 = 0.f, a2 = 0.f, a3 = 0.f;
    for (int i = s0; i < s1; ++i) {
        int rec = edg[i];
        int src = rec >> 13;
        int ty = (rec >> 10) & 7;
        int p = rec & 1023;
        const unsigned short* cr =
            ((ty < 4) ? CH0 + (size_t)ty * NN * HH : CH45 + (size_t)(ty - 4) * NN * HH)
            + (size_t)src * HH;
        const unsigned short* gr = gate + (size_t)p * HH;
        a0 += bf2f(cr[j0]) * bf2f(gr[j0]);
        a1 += bf2f(cr[j1]) * bf2f(gr[j1]);
        a2 += bf2f(cr[j2]) * bf2f(gr[j2]);
        if (j3 < HH) a3 += bf2f(cr[j3]) * bf2f(gr[j3]);
    }
    float iv = inv[n];
    unsigned short* mr = msgb + (size_t)n * HH;
    mr[j0] = f2bf(a0 * iv); mr[j1] = f2bf(a1 * iv); mr[j2] = f2bf(a2 * iv);
    if (j3 < HH) mr[j3] = f2bf(a3 * iv);
}

// Fused GRU, 2-plane register schedule. M=64 tile; 4 waves column-split {4,3,3,3},
// each wave all 64 rows (4 row-frags). A-tiles (h f32->bf16, msg bf16) snapshotted in
// LDS before any write -> in-place h update is race-free (blocks own disjoint rows,
// waves own disjoint cols; the hv re-read below is this wave's own cols).
__global__ __launch_bounds__(256, 2) void gru_fused(
    float* h, const float* hsrc, const unsigned short* __restrict__ msgb,
    const unsigned short* __restrict__ BPir, const unsigned short* __restrict__ BPiz,
    const unsigned short* __restrict__ BPin, const unsigned short* __restrict__ BPhr,
    const unsigned short* __restrict__ BPhz, const unsigned short* __restrict__ BPhn,
    const float* __restrict__ bih, const float* __restrict__ bhh) {
    __shared__ unsigned short hl[64 * LDA];
    __shared__ unsigned short ml[64 * LDA];
    const int t = threadIdx.x;
    const int w = t >> 6;
    const int l = t & 63;
    const int lm = l & 15, lh = l >> 4;
    const int cs = w * 3 + (w > 0);     // 0,4,7,10
    const int ncf = w ? 3 : 4;
    const int base = blockIdx.x * 64;

    for (int idx = t; idx < 64 * 101; idx += 256) {
        int row = idx / 101;
        int c = idx - row * 101;
        int gn = base + row;
        float2 vh = make_float2(0.f, 0.f);
        ushort2 vm; vm.x = 0; vm.y = 0;
        if (gn < NN) {
            vh = *reinterpret_cast<const float2*>(&hsrc[(size_t)gn * HH + c * 2]);
            vm = *reinterpret_cast<const ushort2*>(&msgb[(size_t)gn * HH + c * 2]);
        }
        ushort2 bh; bh.x = f2bf(vh.x); bh.y = f2bf(vh.y);
        *reinterpret_cast<ushort2*>(&hl[row * LDA + c * 2]) = bh;
        *reinterpret_cast<ushort2*>(&ml[row * LDA + c * 2]) = vm;
    }
    for (int idx = t; idx < 64 * 11; idx += 256) {
        int row = idx / 11;
        int c = idx - row * 11;
        ushort2 z; z.x = 0; z.y = 0;
        *reinterpret_cast<ushort2*>(&hl[row * LDA + HH + c * 2]) = z;
        *reinterpret_cast<ushort2*>(&ml[row * LDA + HH + c * 2]) = z;
    }
    __syncthreads();

    v4f P1[4][4], P2[4][4];
#pragma unroll
    for (int ci = 0; ci < 4; ++ci)
#pragma unroll
        for (int rf = 0; rf < 4; ++rf) P1[ci][rf] = (v4f){0.f, 0.f, 0.f, 0.f};

    // loop 1: P1 = msg@Wir + h@Whr
#pragma unroll 1
    for (int kt = 0; kt < NKT; ++kt) {
        short8 ah[4], am[4];
#pragma unroll
        for (int rf = 0; rf < 4; ++rf) {
            ah[rf] = *reinterpret_cast<const short8*>(&hl[(rf * 16 + lm) * LDA + kt * 32 + lh * 8]);
            am[rf] = *reinterpret_cast<const short8*>(&ml[(rf * 16 + lm) * LDA + kt * 32 + lh * 8]);
        }
#pragma unroll
        for (int ci = 0; ci < 4; ++ci) {
            if (ci < ncf) {
                size_t bo = ((size_t)((cs + ci) * NKT + kt) * 64 + l) * 8;
                short8 bir = *reinterpret_cast<const short8*>(&BPir[bo]);
                short8 bhr = *reinterpret_cast<const short8*>(&BPhr[bo]);
#pragma unroll
                for (int rf = 0; rf < 4; ++rf) {
                    P1[ci][rf] = __builtin_amdgcn_mfma_f32_16x16x32_bf16(am[rf], bir, P1[ci][rf], 0, 0, 0);
                    P1[ci][rf] = __builtin_amdgcn_mfma_f32_16x16x32_bf16(ah[rf], bhr, P1[ci][rf], 0, 0, 0);
                }
            }
        }
    }
    // r = sig(P1 + br)
#pragma unroll
    for (int ci = 0; ci < 4; ++ci) {
        if (ci < ncf) {
            int col = (cs + ci) * 16 + lm;
            float br = (col < HH) ? (bih[col] + bhh[col]) : 0.f;
#pragma unroll
            for (int rf = 0; rf < 4; ++rf)
#pragma unroll
                for (int r = 0; r < 4; ++r)
                    P1[ci][rf][r] = sigf(P1[ci][rf][r] + br);
        }
    }

    // loop 2: P2 = h@Whn
#pragma unroll
    for (int ci = 0; ci < 4; ++ci)
#pragma unroll
        for (int rf = 0; rf < 4; ++rf) P2[ci][rf] = (v4f){0.f, 0.f, 0.f, 0.f};
#pragma unroll 2
    for (int kt = 0; kt < NKT; ++kt) {
        short8 ah[4];
#pragma unroll
        for (int rf = 0; rf < 4; ++rf)
            ah[rf] = *reinterpret_cast<const short8*>(&hl[(rf * 16 + lm) * LDA + kt * 32 + lh * 8]);
#pragma unroll
        for (int ci = 0; ci < 4; ++ci) {
            if (ci < ncf) {
                size_t bo = ((size_t)((cs + ci) * NKT + kt) * 64 + l) * 8;
                short8 bhn = *reinterpret_cast<const short8*>(&BPhn[bo]);
#pragma unroll
                for (int rf = 0; rf < 4; ++rf)
                    P2[ci][rf] = __builtin_amdgcn_mfma_f32_16x16x32_bf16(ah[rf], bhn, P2[ci][rf], 0, 0, 0);
            }
        }
    }
    // P2 = bin + r*(P2 + bnh)
#pragma unroll
    for (int ci = 0; ci < 4; ++ci) {
        if (ci < ncf) {
            int col = (cs + ci) * 16 + lm;
            float bn_i = (col < HH) ? bih[404 + col] : 0.f;
            float bn_h = (col < HH) ? bhh[404 + col] : 0.f;
#pragma unroll
            for (int rf = 0; rf < 4; ++rf)
#pragma unroll
                for (int r = 0; r < 4; ++r)
                    P2[ci][rf][r] = bn_i + P1[ci][rf][r] * (P2[ci][rf][r] + bn_h);
        }
    }

    // loop 3: P2 += msg@Win; then n = tanh(P2)
#pragma unroll 2
    for (int kt = 0; kt < NKT; ++kt) {
        short8 am[4];
#pragma unroll
        for (int rf = 0; rf < 4; ++rf)
            am[rf] = *reinterpret_cast<const short8*>(&ml[(rf * 16 + lm) * LDA + kt * 32 + lh * 8]);
#pragma unroll
        for (int ci = 0; ci < 4; ++ci) {
            if (ci < ncf) {
                size_t bo = ((size_t)((cs + ci) * NKT + kt) * 64 + l) * 8;
                short8 bin_ = *reinterpret_cast<const short8*>(&BPin[bo]);
#pragma unroll
                for (int rf = 0; rf < 4; ++rf)
                    P2[ci][rf] = __builtin_amdgcn_mfma_f32_16x16x32_bf16(am[rf], bin_, P2[ci][rf], 0, 0, 0);
            }
        }
    }
#pragma unroll
    for (int ci = 0; ci < 4; ++ci)
        if (ci < ncf)
#pragma unroll
            for (int rf = 0; rf < 4; ++rf)
#pragma unroll
                for (int r = 0; r < 4; ++r)
                    P2[ci][rf][r] = tanhf(P2[ci][rf][r]);

    // loop 4: P1 = msg@Wiz + h@Whz
#pragma unroll
    for (int ci = 0; ci < 4; ++ci)
#pragma unroll
        for (int rf = 0; rf < 4; ++rf) P1[ci][rf] = (v4f){0.f, 0.f, 0.f, 0.f};
#pragma unroll 1
    for (int kt = 0; kt < NKT; ++kt) {
        short8 ah[4], am[4];
#pragma unroll
        for (int rf = 0; rf < 4; ++rf) {
            ah[rf] = *reinterpret_cast<const short8*>(&hl[(rf * 16 + lm) * LDA + kt * 32 + lh * 8]);
            am[rf] = *reinterpret_cast<const short8*>(&ml[(rf * 16 + lm) * LDA + kt * 32 + lh * 8]);
        }
#pragma unroll
        for (int ci = 0; ci < 4; ++ci) {
            if (ci < ncf) {
                size_t bo = ((size_t)((cs + ci) * NKT + kt) * 64 + l) * 8;
                short8 biz = *reinterpret_cast<const short8*>(&BPiz[bo]);
                short8 bhz = *reinterpret_cast<const short8*>(&BPhz[bo]);
#pragma unroll
                for (int rf = 0; rf < 4; ++rf) {
                    P1[ci][rf] = __builtin_amdgcn_mfma_f32_16x16x32_bf16(am[rf], biz, P1[ci][rf], 0, 0, 0);
                    P1[ci][rf] = __builtin_amdgcn_mfma_f32_16x16x32_bf16(ah[rf], bhz, P1[ci][rf], 0, 0, 0);
                }
            }
        }
    }

    // z = sig(P1+bz); h' = (1-z)*n + z*h   (hv read from hsrc: own cols only)
#pragma unroll
    for (int ci = 0; ci < 4; ++ci) {
        if (ci < ncf) {
            int col = (cs + ci) * 16 + lm;
            if (col < HH) {
                float bz = bih[202 + col] + bhh[202 + col];
#pragma unroll
                for (int rf = 0; rf < 4; ++rf) {
#pragma unroll
                    for (int r = 0; r < 4; ++r) {
                        int row = base + rf * 16 + lh * 4 + r;
                        if (row < NN) {
                            float z = sigf(P1[ci][rf][r] + bz);
                            float hv = hsrc[(size_t)row * HH + col];
                            h[(size_t)row * HH + col] = (1.0f - z) * P2[ci][rf][r] + z * hv;
                        }
                    }
                }
            }
        }
    }
}

extern "C" void kernel_launch(void* const* d_in, const int* in_sizes, int n_in,
                              void* d_out, int out_size, void* d_ws, size_t ws_size,
                              hipStream_t stream) {
    const float* node_states = (const float*)d_in[0];
    const int*   el          = (const int*)d_in[1];
    const int*   pl          = (const int*)d_in[2];
    const float* msg_W       = (const float*)d_in[3];
    const float* msg_b       = (const float*)d_in[4];
    const float* pos_W       = (const float*)d_in[5];
    const float* pos_b       = (const float*)d_in[6];
    const float* gWih        = (const float*)d_in[7];
    const float* gWhh        = (const float*)d_in[8];
    const float* gbih        = (const float*)d_in[9];
    const float* gbhh        = (const float*)d_in[10];

    float* out  = (float*)d_out;
    float* h    = out;                               // [N,H] final h
    float* out2 = out + (size_t)NN * HH;             // chunks ty=4,5 during steps; node_states at end

    unsigned short* CH0  = (unsigned short*)d_ws;                    // 4 slabs bf16 [N,H]
    unsigned short* CH45 = (unsigned short*)out2;                    // 2 slabs bf16 [N,H]
    unsigned short* MSGB = CH0 + (size_t)4 * NN * HH;                // [N,H] bf16
    unsigned short* GATE = MSGB + (size_t)NN * HH;                   // [1024,H] bf16
    float* INV  = (float*)(GATE + (size_t)PMX * HH + 8);             // [N] (pad keeps 4B align)
    int* CNT    = (int*)(INV + NN);                                  // [N]
    int* OFF    = CNT + NN;                                          // [N+4]
    int* CUR    = OFF + NN + 4;                                      // [N]
    int* BS     = CUR + NN;                                          // [256]
    int* EDG    = BS + 256;                                          // [600000]
    unsigned short* BPA = (unsigned short*)(EDG + NEDG);             // 12 packs
    unsigned short* BPp  = BPA;
    unsigned short* BPir = BPA + (size_t)6 * PKSZ;
    unsigned short* BPiz = BPA + (size_t)7 * PKSZ;
    unsigned short* BPin = BPA + (size_t)8 * PKSZ;
    unsigned short* BPhr = BPA + (size_t)9 * PKSZ;
    unsigned short* BPhz = BPA + (size_t)10 * PKSZ;
    unsigned short* BPhn = BPA + (size_t)11 * PKSZ;

    const size_t NH = (size_t)NN * HH;
    hipMemsetAsync(CNT, 0, NN * sizeof(int), stream);
    gate_kernel<<<PMX, 256, 0, stream>>>(pos_W, pos_b, GATE);
    const int pkb = (PKSZ + 255) / 256;
    for (int ty = 0; ty < 6; ++ty)
        pack_kernel<<<pkb, 256, 0, stream>>>(msg_W, 1212, 0, ty * HH, 0, BPp + (size_t)ty * PKSZ);
    pack_kernel<<<pkb, 256, 0, stream>>>(gWih, 0, 0,   0, 1, BPir);
    pack_kernel<<<pkb, 256, 0, stream>>>(gWih, 0, 202, 0, 1, BPiz);
    pack_kernel<<<pkb, 256, 0, stream>>>(gWih, 0, 404, 0, 1, BPin);
    pack_kernel<<<pkb, 256, 0, stream>>>(gWhh, 0, 0,   0, 1, BPhr);
    pack_kernel<<<pkb, 256, 0, stream>>>(gWhh, 0, 202, 0, 1, BPhz);
    pack_kernel<<<pkb, 256, 0, stream>>>(gWhh, 0, 404, 0, 1, BPhn);

    const int nsb = (NN + 255) / 256;    // 196
    count_kernel<<<(NEDG + 255) / 256, 256, 0, stream>>>(el, CNT);
    scan1_kernel<<<nsb, 256, 0, stream>>>(CNT, OFF, BS);
    scan2_kernel<<<1, 256, 0, stream>>>(BS, nsb);
    scan3_kernel<<<nsb, 256, 0, stream>>>(OFF, BS, CUR);
    inv_kernel<<<nsb, 256, 0, stream>>>(CNT, INV);
    fill_kernel<<<(NEDG + 255) / 256, 256, 0, stream>>>(el, pl, CUR, EDG);

    const int gblocks = (NN + 63) / 64;  // 782
    for (int step = 0; step < 2; ++step) {
        const float* hsrc = (step == 0) ? node_states : h;
        prop_fused<<<gblocks, 256, 0, stream>>>(hsrc, BPp, msg_b, CH0, CH45);
        agg_kernel<<<(NN + 3) / 4, 256, 0, stream>>>(CH0, CH45, OFF, EDG, GATE, INV, MSGB);
        gru_fused<<<gblocks, 256, 0, stream>>>(h, hsrc, MSGB, BPir, BPiz, BPin,
                                               BPhr, BPhz, BPhn, gbih, gbhh);
    }
    hipMemcpyAsync(out2, node_states, NH * sizeof(float), hipMemcpyDeviceToDevice, stream);
}